// Round 19
// baseline (328.609 us; speedup 1.0000x reference)
//
#include <hip/hip_runtime.h>
#include <hip/hip_bf16.h>

#define B 8
#define N1 8192
#define N4 2048
#define CH 128
#define KNN 32
#define ROWS_PER_B (N4 * KNN)          // 65536 rows per batch in the [B,N,K] flattening
#define ROWS_TOTAL (B * ROWS_PER_B)    // 524288
#define NPTS (B * N4)                  // 16384 total points
#define FLOWLR_OFF (B * 3 * N1)        // flow_lr starts after flow in d_out

typedef unsigned int uint;
typedef unsigned short ushort;
typedef unsigned long long u64;
typedef __attribute__((ext_vector_type(8))) short short8;
typedef __attribute__((ext_vector_type(4))) float f32x4;

union U16 { uint4 u; short8 s; };

__device__ __forceinline__ float bf2f(ushort u) {
    union { uint i; float f; } v; v.i = ((uint)u) << 16; return v.f;
}
__device__ __forceinline__ ushort f2b(float f) {
    __hip_bfloat16 h = __float2bfloat16(f);
    return *(ushort*)&h;
}

// ---------------- prep (merged): W converters + xyz transpose + stats zero + feats transpose ----------------
// blocks [0,400): elementwise prep; blocks [400,2448): feat-transpose tiles (flat 256 threads as 32x8).
__global__ void k_prep(const float* __restrict__ xyz_s4, float* __restrict__ xyz4,
                       const float* __restrict__ sa1_W1, const float* __restrict__ sa2_W1,
                       const float* __restrict__ sa1_W2, const float* __restrict__ sa2_W2,
                       ushort* __restrict__ W1b1, ushort* __restrict__ W1b2,
                       ushort* __restrict__ W2b1, ushort* __restrict__ W2b2,
                       float* __restrict__ stats,
                       const float* __restrict__ feats, ushort* __restrict__ featTb)
{
    __shared__ float tile[32][33];
    if (blockIdx.x < 400) {
        int i = blockIdx.x * 256 + threadIdx.x;
        if (i < 43008) {
            const float* W = (i < 21504) ? sa1_W1 : sa2_W1;
            ushort* o = (i < 21504) ? W1b1 : W1b2;
            int j = (i < 21504) ? i : i - 21504;
            int d = j / 168, c = j - d * 168;
            float v = 0.f;
            if (c < 128)      v = W[d * 131 + 3 + c];
            else if (c < 131) v = W[d * 131 + (c - 128)];
            o[j] = f2b(v);
        } else if (i < 77824) {
            const float* W = (i < 60416) ? sa1_W2 : sa2_W2;
            ushort* o = (i < 60416) ? W2b1 : W2b2;
            int j = (i < 60416) ? i - 43008 : i - 60416;
            int d = j / 136, c = j - d * 136;
            o[j] = (c < 128) ? f2b(W[d * 128 + c]) : (ushort)0;
        } else if (i < 94208) {
            int g = i - 77824;
            int b = g >> 11, n = g & (N4 - 1);
            xyz4[g * 3 + 0] = xyz_s4[(b * 3 + 0) * N4 + n];
            xyz4[g * 3 + 1] = xyz_s4[(b * 3 + 1) * N4 + n];
            xyz4[g * 3 + 2] = xyz_s4[(b * 3 + 2) * N4 + n];
        } else if (i < 102400) {
            stats[i - 94208] = 0.f;    // zeros statsA..statsD (contiguous 8192 floats)
        }
    } else {
        int f = blockIdx.x - 400;       // 2048 tiles: b(8) x nb(64) x cb(4)
        int b = f >> 8, rem = f & 255, nb = rem >> 2, cb = rem & 3;
        int tx = threadIdx.x & 31, ty = threadIdx.x >> 5;   // 32 x 8
        int n0 = nb * 32, c0 = cb * 32;
#pragma unroll
        for (int i = 0; i < 4; ++i) {
            int c = c0 + ty + 8 * i;
            tile[ty + 8 * i][tx] = feats[((size_t)b * CH + c) * N4 + n0 + tx];
        }
        __syncthreads();
#pragma unroll
        for (int i = 0; i < 4; ++i) {
            int n = n0 + ty + 8 * i;
            featTb[((size_t)b * N4 + n) * CH + c0 + tx] = f2b(tile[tx][ty + 8 * i]);
        }
    }
}

// ---------------- KNN via exact threshold-select (interpolation search + order-statistic gap exit) ----------------
__global__ __launch_bounds__(512) void k_knn(const float* __restrict__ xyz4, int* __restrict__ idxout) {
    __shared__ float pts[N4 * 3];
    int b = blockIdx.x >> 8;            // 256 blocks per batch
    int qbase = (blockIdx.x & 255) * 8;
    for (int i = threadIdx.x; i < N4 * 3; i += 512) pts[i] = xyz4[(size_t)b * N4 * 3 + i];
    __syncthreads();
    int wave = threadIdx.x >> 6, lane = threadIdx.x & 63;
    int qn = qbase + wave;
    float qx = pts[qn * 3 + 0], qy = pts[qn * 3 + 1], qz = pts[qn * 3 + 2];
    float d[32];
#pragma unroll
    for (int t = 0; t < 32; ++t) {
        int c = t * 64 + lane;
        float dx = pts[c * 3 + 0] - qx;
        float dy = pts[c * 3 + 1] - qy;
        float dz = pts[c * 3 + 2] - qz;
        d[t] = dx * dx + dy * dy + dz * dz;
    }
    uint lo = 0u, hi = 0x7F800000u;
    int cLT = 0, cHI = N4;
    float T;
    bool strict = false;
    int it = 0;
    for (;;) {
        if (hi - lo <= 1u) { T = __uint_as_float(lo); break; }
        if (cHI - cLT == 1) {
            float flo = __uint_as_float(lo), fhi = __uint_as_float(hi);
            float m = 3.4e38f;
#pragma unroll
            for (int t = 0; t < 32; ++t) {
                float dv = d[t];
                if (dv >= flo && dv < fhi) m = fminf(m, dv);
            }
#pragma unroll
            for (int s = 1; s < 64; s <<= 1) m = fminf(m, __shfl_xor(m, s, 64));
            T = m;
            break;
        }
        uint mid;
        if ((it & 3) == 0) {
            mid = (lo + hi) >> 1;
        } else {
            float flo = __uint_as_float(lo), fhi = __uint_as_float(hi);
            float fm = flo + (fhi - flo) * ((float)(KNN - cLT) / (float)(cHI - cLT));
            mid = __float_as_uint(fm);
            if (mid <= lo) mid = lo + 1u;
            if (mid >= hi) mid = hi - 1u;
        }
        float fmid = __uint_as_float(mid);
        int c = 0;
#pragma unroll
        for (int t = 0; t < 32; ++t) c += __popcll(__ballot(d[t] < fmid));
        if (c == KNN) { T = fmid; strict = true; break; }
        if (c < KNN) { lo = mid; cLT = c; } else { hi = mid; cHI = c; }
        ++it;
    }
    int outb = (b * N4 + qn) * KNN;
    u64 lmlt = (1ull << lane) - 1ull;
    if (strict) {
        int baseLT = 0;
#pragma unroll
        for (int t = 0; t < 32; ++t) {
            bool lt = d[t] < T;
            u64 m = __ballot(lt);
            if (lt) idxout[outb + baseLT + __popcll(m & lmlt)] = t * 64 + lane;
            baseLT += __popcll(m);
        }
    } else {
        int baseLT = 0, baseEQ = cLT;
#pragma unroll
        for (int t = 0; t < 32; ++t) {
            bool lt = d[t] < T;
            u64 m = __ballot(lt);
            if (lt) idxout[outb + baseLT + __popcll(m & lmlt)] = t * 64 + lane;
            baseLT += __popcll(m);
            bool eq = (d[t] == T);
            u64 me = __ballot(eq);
            if (eq) {
                int rk = baseEQ + __popcll(me & lmlt);
                if (rk < KNN) idxout[outb + rk] = t * 64 + lane;
            }
            baseEQ += __popcll(me);
        }
    }
}

// ---------------- dense z GEMM: z[p] = [in_p | xyz_p] @ W1^T -> bf16 out (LDS repack, coalesced) ----------------
__global__ __launch_bounds__(256) void k_dense(
    const ushort* __restrict__ Fb, const float* __restrict__ xyz4,
    const ushort* __restrict__ W1b, ushort* __restrict__ z,
    const float* __restrict__ stats)
{
    __shared__ __align__(16) ushort hs[64][168];
    __shared__ float sinvs[128], sprem[128];   // sinv, mean*sinv
    int t = threadIdx.x;
    int r = t >> 2, q = t & 3;
    int l = t & 63, w = t >> 6, lr = l & 15, lg = l >> 4;
    int g0 = blockIdx.x * 64;
    int b = g0 >> 11;                    // 2048 points per batch
    if (stats) {
        if (t < 128) {
            float s = stats[b * CH + t], q2 = stats[B * CH + b * CH + t];
            float mean = s * (1.f / ROWS_PER_B);
            float var = q2 * (1.f / ROWS_PER_B) - mean * mean;
            float iv = rsqrtf(var + 1e-5f);
            sinvs[t] = iv; sprem[t] = mean * iv;
        }
        __syncthreads();
    }
    {
        int p = g0 + r;
        const uint4* src = (const uint4*)(Fb + (size_t)p * CH) + q * 4;
        uint4* dst = (uint4*)&hs[r][q * 32];
        if (stats) {
#pragma unroll
            for (int m = 0; m < 4; ++m) {
                uint4 v = src[m];
                const uint* pv = (const uint*)&v;
                ushort o[8];
#pragma unroll
                for (int e = 0; e < 4; ++e) {
                    int c = q * 32 + m * 8 + e * 2;
                    o[e * 2]     = f2b(fmaxf(fmaf(bf2f((ushort)(pv[e] & 0xffff)), sinvs[c],     -sprem[c]),     0.f));
                    o[e * 2 + 1] = f2b(fmaxf(fmaf(bf2f((ushort)(pv[e] >> 16)),    sinvs[c + 1], -sprem[c + 1]), 0.f));
                }
                dst[m] = *(uint4*)o;
            }
        } else {
#pragma unroll
            for (int m = 0; m < 4; ++m) dst[m] = src[m];
        }
        uint4 zz = make_uint4(0, 0, 0, 0);
        *(uint4*)&hs[r][128 + q * 8] = zz;
        if (q == 0) {
            *(uint4*)&hs[r][160] = zz;
            hs[r][128] = f2b(xyz4[p * 3 + 0]);
            hs[r][129] = f2b(xyz4[p * 3 + 1]);
            hs[r][130] = f2b(xyz4[p * 3 + 2]);
        }
    }
    U16 bf[5][2];
#pragma unroll
    for (int kc = 0; kc < 5; ++kc)
#pragma unroll
        for (int jj = 0; jj < 2; ++jj)
            bf[kc][jj].u = *(const uint4*)&W1b[(size_t)(w * 32 + jj * 16 + lr) * 168 + kc * 32 + lg * 8];
    __syncthreads();
    f32x4 acc[4][2];
    f32x4 z4 = {0.f, 0.f, 0.f, 0.f};
#pragma unroll
    for (int i = 0; i < 4; ++i) { acc[i][0] = z4; acc[i][1] = z4; }
#pragma unroll
    for (int kc = 0; kc < 5; ++kc) {
        U16 a[4];
#pragma unroll
        for (int i = 0; i < 4; ++i) a[i].u = *(const uint4*)&hs[16 * i + lr][kc * 32 + lg * 8];
#pragma unroll
        for (int i = 0; i < 4; ++i)
#pragma unroll
            for (int jj = 0; jj < 2; ++jj)
                acc[i][jj] = __builtin_amdgcn_mfma_f32_16x16x32_bf16(a[i].s, bf[kc][jj].s, acc[i][jj], 0, 0, 0);
    }
    __syncthreads();   // hs reads done -> reuse as bf16 repack buffer
#pragma unroll
    for (int jj = 0; jj < 2; ++jj)
#pragma unroll
        for (int i = 0; i < 4; ++i)
#pragma unroll
            for (int rg = 0; rg < 4; ++rg)
                hs[16 * i + lg * 4 + rg][w * 32 + jj * 16 + lr] = f2b(acc[i][jj][rg]);
    __syncthreads();
    {
        uint4* dst = (uint4*)(z + (size_t)(g0 + r) * CH + q * 32);
#pragma unroll
        for (int m = 0; m < 4; ++m) dst[m] = *(const uint4*)&hs[r][q * 32 + m * 8];
    }
}

// ---------------- gather-stats: per-(b,c) sum/sumsq of y1 = z[j]-u[n]; z bf16, u on the fly ----------------
__global__ __launch_bounds__(256) void k_gstats(
    const ushort* __restrict__ z, const int* __restrict__ idx,
    const float* __restrict__ xyz4, const ushort* __restrict__ W1b,
    float* __restrict__ stats)
{
    __shared__ int idxs[32 * KNN];
    __shared__ float sacc[128], sqacc[128];
    __shared__ ushort w1x[384];          // [c][a], c*3+a
    int t = threadIdx.x;
    int gpb = blockIdx.x * 32;
    int b = gpb >> 11;
    for (int ii = t; ii < 32 * KNN; ii += 256) idxs[ii] = idx[(size_t)gpb * KNN + ii];
    if (t < 128) {
        sacc[t] = 0.f; sqacc[t] = 0.f;
        w1x[t * 3 + 0] = W1b[t * 168 + 128];
        w1x[t * 3 + 1] = W1b[t * 168 + 129];
        w1x[t * 3 + 2] = W1b[t * 168 + 130];
    }
    __syncthreads();
    int li = t >> 3, cq = (t & 7) * 16;
    int gp = gpb + li;
    float s[16], qa[16];
#pragma unroll
    for (int m = 0; m < 16; ++m) { s[m] = 0.f; qa[m] = 0.f; }
    int zb = b * N4;
#pragma unroll 4
    for (int k = 0; k < KNN; ++k) {
        int j = idxs[li * KNN + k];
        const uint4* zr = (const uint4*)(z + (size_t)(zb + j) * CH + cq);  // 16 bf16 = 2x uint4
        uint4 v0 = zr[0], v1 = zr[1];
        const uint* pv = (const uint*)&v0;
#pragma unroll
        for (int u8 = 0; u8 < 8; ++u8) {
            uint vv = (u8 < 4) ? pv[u8] : ((const uint*)&v1)[u8 - 4];
            float f0 = bf2f((ushort)(vv & 0xffff));
            float f1 = bf2f((ushort)(vv >> 16));
            s[u8 * 2] += f0;     qa[u8 * 2] += f0 * f0;
            s[u8 * 2 + 1] += f1; qa[u8 * 2 + 1] += f1 * f1;
        }
    }
    float x = bf2f(f2b(xyz4[gp * 3 + 0]));
    float y = bf2f(f2b(xyz4[gp * 3 + 1]));
    float zc = bf2f(f2b(xyz4[gp * 3 + 2]));
#pragma unroll
    for (int m = 0; m < 16; ++m) {
        int c = cq + m;
        float uu = x * bf2f(w1x[c * 3]) + y * bf2f(w1x[c * 3 + 1]) + zc * bf2f(w1x[c * 3 + 2]);
        float ss = s[m], qq = qa[m];
        atomicAdd(&sacc[c], ss - 32.f * uu);
        atomicAdd(&sqacc[c], qq - 2.f * uu * ss + 32.f * uu * uu);
    }
    __syncthreads();
    if (t < 128) {
        atomicAdd(&stats[b * CH + t], sacc[t]);
        atomicAdd(&stats[B * CH + b * CH + t], sqacc[t]);
    }
}

// ---------------- fused pass: 256 rows/block, dbuf LDS; z bf16; affine-folded normalization ----------------
__global__ __launch_bounds__(256) void k_fused2(
    const ushort* __restrict__ z, const int* __restrict__ idx,
    const float* __restrict__ xyz4, const ushort* __restrict__ W1b,
    const ushort* __restrict__ W2b, const float* __restrict__ stats1,
    float* __restrict__ stats2, ushort* __restrict__ ymax)
{
    __shared__ __align__(16) ushort hs[2][64][136];
    __shared__ float sinvs[128], smean[128];
    __shared__ float pre[8][128];        // (u + mean) * sinv per point
    __shared__ ushort w1x[384];
    int t = threadIdx.x;
    int g0 = blockIdx.x * 256;          // 256 rows = 8 points
    int b = g0 >> 16;
    int gp0 = g0 >> 5;
    int l = t & 63, w = t >> 6, lr = l & 15, lg = l >> 4;
    U16 b2f[4][2];
#pragma unroll
    for (int kc = 0; kc < 4; ++kc)
#pragma unroll
        for (int jj = 0; jj < 2; ++jj)
            b2f[kc][jj].u = *(const uint4*)&W2b[(size_t)(w * 32 + jj * 16 + lr) * 136 + kc * 32 + lg * 8];
    if (t < 128) {
        float s = stats1[b * CH + t], q2 = stats1[B * CH + b * CH + t];
        float mean = s * (1.f / ROWS_PER_B);
        float var = q2 * (1.f / ROWS_PER_B) - mean * mean;
        float iv = rsqrtf(var + 1e-5f);
        sinvs[t] = iv; smean[t] = mean;
        w1x[t * 3 + 0] = W1b[t * 168 + 128];
        w1x[t * 3 + 1] = W1b[t * 168 + 129];
        w1x[t * 3 + 2] = W1b[t * 168 + 130];
    }
    __syncthreads();
    {   // pre[p][c] = (u[p][c] + mean[c]) * sinv[c]; 8 points x 128 cols, 4 cols/thread
        int p = t >> 5, i = t & 31;
        float x = bf2f(f2b(xyz4[(gp0 + p) * 3 + 0]));
        float y = bf2f(f2b(xyz4[(gp0 + p) * 3 + 1]));
        float zc = bf2f(f2b(xyz4[(gp0 + p) * 3 + 2]));
#pragma unroll
        for (int jj = 0; jj < 4; ++jj) {
            int c = i * 4 + jj;
            float uu = x * bf2f(w1x[c * 3]) + y * bf2f(w1x[c * 3 + 1]) + zc * bf2f(w1x[c * 3 + 2]);
            pre[p][c] = (uu + smean[c]) * sinvs[c];
        }
    }
    int r = t >> 2, q = t & 3;
    uint4 zv[4];
    {
        int j = idx[g0 + r];
        const uint4* zr = (const uint4*)(z + (size_t)(b * N4 + j) * CH + q * 32);
#pragma unroll
        for (int m = 0; m < 4; ++m) zv[m] = zr[m];
    }
    float sA[2] = {0.f, 0.f}, qA[2] = {0.f, 0.f};
    f32x4 z4 = {0.f, 0.f, 0.f, 0.f};
    __syncthreads();   // sinvs/pre ready
    for (int st = 0; st < 4; ++st) {
        ushort (*buf)[136] = hs[st & 1];
        {
            int urow = (st * 64 + r) >> 5;
#pragma unroll
            for (int mm = 0; mm < 4; ++mm) {
                const uint* pv = (const uint*)&zv[mm];
                ushort o[8];
#pragma unroll
                for (int e = 0; e < 4; ++e) {
                    int c = q * 32 + mm * 8 + e * 2;
                    float f0 = bf2f((ushort)(pv[e] & 0xffff));
                    float f1 = bf2f((ushort)(pv[e] >> 16));
                    o[e * 2]     = f2b(fmaxf(fmaf(f0, sinvs[c],     -pre[urow][c]),     0.f));
                    o[e * 2 + 1] = f2b(fmaxf(fmaf(f1, sinvs[c + 1], -pre[urow][c + 1]), 0.f));
                }
                *(uint4*)&buf[r][q * 32 + mm * 8] = *(uint4*)o;
            }
            if (q == 0) { uint4 zz = make_uint4(0, 0, 0, 0); *(uint4*)&buf[r][128] = zz; }
        }
        __syncthreads();
        if (st < 3) {
            int j = idx[g0 + (st + 1) * 64 + r];
            const uint4* zr = (const uint4*)(z + (size_t)(b * N4 + j) * CH + q * 32);
#pragma unroll
            for (int m = 0; m < 4; ++m) zv[m] = zr[m];
        }
        f32x4 acc[4][2];
#pragma unroll
        for (int i = 0; i < 4; ++i) { acc[i][0] = z4; acc[i][1] = z4; }
#pragma unroll
        for (int kc = 0; kc < 4; ++kc) {
            U16 a[4];
#pragma unroll
            for (int i = 0; i < 4; ++i) a[i].u = *(const uint4*)&buf[16 * i + lr][kc * 32 + lg * 8];
#pragma unroll
            for (int i = 0; i < 4; ++i)
#pragma unroll
                for (int jj = 0; jj < 2; ++jj)
                    acc[i][jj] = __builtin_amdgcn_mfma_f32_16x16x32_bf16(a[i].s, b2f[kc][jj].s, acc[i][jj], 0, 0, 0);
        }
        int gpA = gp0 + st * 2;
#pragma unroll
        for (int jj = 0; jj < 2; ++jj) {
            int c = w * 32 + jj * 16 + lr;
            float m0 = -3.4e38f, m1 = -3.4e38f;
#pragma unroll
            for (int i = 0; i < 4; ++i)
#pragma unroll
                for (int rg = 0; rg < 4; ++rg) {
                    float v = acc[i][jj][rg];
                    sA[jj] += v; qA[jj] += v * v;
                    if (i < 2) m0 = fmaxf(m0, v); else m1 = fmaxf(m1, v);
                }
            m0 = fmaxf(m0, __shfl_xor(m0, 16, 64)); m0 = fmaxf(m0, __shfl_xor(m0, 32, 64));
            m1 = fmaxf(m1, __shfl_xor(m1, 16, 64)); m1 = fmaxf(m1, __shfl_xor(m1, 32, 64));
            if (lg == 0) {
                ymax[(size_t)gpA * CH + c] = f2b(m0);
                ymax[(size_t)(gpA + 1) * CH + c] = f2b(m1);
            }
        }
    }
#pragma unroll
    for (int jj = 0; jj < 2; ++jj) {
        int c = w * 32 + jj * 16 + lr;
        float ss = sA[jj], qq = qA[jj];
        ss += __shfl_xor(ss, 16, 64); ss += __shfl_xor(ss, 32, 64);
        qq += __shfl_xor(qq, 16, 64); qq += __shfl_xor(qq, 32, 64);
        if (lg == 0) {
            atomicAdd(&stats2[b * CH + c], ss);
            atomicAdd(&stats2[B * CH + b * CH + c], qq);
        }
    }
}

// ---------------- FC head: relu(normrelu(ymax)@W1^T+b1) @ W2^T + b2 -> flow_lr [B,3,N4] ----------------
__global__ __launch_bounds__(256, 1) void k_fc(
    const ushort* __restrict__ Ymax, const float* __restrict__ stats,
    const float* __restrict__ W1, const float* __restrict__ b1,
    const float* __restrict__ W2, const float* __restrict__ b2,
    float* __restrict__ out)
{
    __shared__ float hs[64][132];
    __shared__ float ws[128][132];
    __shared__ float sinvs[128], sprem[128];
    int t = threadIdx.x;
    int g0 = blockIdx.x * 64;
    int b = g0 >> 11;
    if (t < 128) {
        float s = stats[b * CH + t], q2 = stats[B * CH + b * CH + t];
        float mean = s * (1.f / ROWS_PER_B);
        float var = q2 * (1.f / ROWS_PER_B) - mean * mean;
        float iv = rsqrtf(var + 1e-5f);
        sinvs[t] = iv; sprem[t] = mean * iv;
    }
    for (int i = t; i < 128 * 132; i += 256) {
        int dd = i / 132, c = i - dd * 132;
        ws[dd][c] = (c < 128) ? W1[dd * 128 + c] : 0.f;
    }
    __syncthreads();
    int r = t >> 2, q = t & 3;
    {
        const uint4* Xrow = (const uint4*)(Ymax + (size_t)(g0 + r) * CH + q * 32);
#pragma unroll
        for (int m = 0; m < 4; ++m) {
            uint4 v = Xrow[m];
            const uint* pv = (const uint*)&v;
            int c0 = q * 32 + m * 8;
#pragma unroll
            for (int e = 0; e < 4; ++e) {
                int c = c0 + 2 * e;
                hs[r][c]     = fmaxf(fmaf(bf2f((ushort)(pv[e] & 0xffff)), sinvs[c],     -sprem[c]),     0.f);
                hs[r][c + 1] = fmaxf(fmaf(bf2f((ushort)(pv[e] >> 16)),    sinvs[c + 1], -sprem[c + 1]), 0.f);
            }
        }
        if (q == 0) *(float4*)&hs[r][128] = make_float4(0.f, 0.f, 0.f, 0.f);
    }
    __syncthreads();
    int tx = t & 15, ty = t >> 4;
    float acc[4][8];
#pragma unroll
    for (int i = 0; i < 4; ++i)
#pragma unroll
        for (int jj = 0; jj < 8; ++jj) acc[i][jj] = 0.f;
    for (int kb = 0; kb < 33; ++kb) {
        float4 a[4]; float4 w[8];
#pragma unroll
        for (int i = 0; i < 4; ++i) a[i] = *(float4*)&hs[ty * 4 + i][kb * 4];
#pragma unroll
        for (int jj = 0; jj < 8; ++jj) w[jj] = *(float4*)&ws[tx + 16 * jj][kb * 4];
#pragma unroll
        for (int i = 0; i < 4; ++i)
#pragma unroll
            for (int jj = 0; jj < 8; ++jj)
                acc[i][jj] += a[i].x * w[jj].x + a[i].y * w[jj].y
                            + a[i].z * w[jj].z + a[i].w * w[jj].w;
    }
    __syncthreads();
#pragma unroll
    for (int jj = 0; jj < 8; ++jj) {
        int c = tx + 16 * jj;
        float bias = b1[c];
#pragma unroll
        for (int i = 0; i < 4; ++i)
            hs[ty * 4 + i][c] = fmaxf(acc[i][jj] + bias, 0.f);
    }
    __syncthreads();
    if (t < 192) {
        int rr = t / 3, o = t - rr * 3;
        float sum = b2[o];
        for (int c = 0; c < 128; ++c) sum += hs[rr][c] * W2[o * 128 + c];
        int g = g0 + rr;
        int bb = g >> 11, n = g & (N4 - 1);
        out[FLOWLR_OFF + ((size_t)bb * 3 + o) * N4 + n] = sum;
    }
}

// ---------------- feature propagation: 3-NN inverse-sqdist interp onto xyz1 ----------------
// u64-packed (ordered-key | idx) top-3: one u64 compare screens a candidate; sorted-insert is a
// 4-selection u64 network inside the (rarely taken per-lane) guard. Selection set and tie rule
// are bit-identical to lexicographic (key, ascending idx) == the strict-< ascending scan.
__global__ __launch_bounds__(256) void k_fp(
    const float* __restrict__ xyz_s1, const float* __restrict__ xyz4,
    float* __restrict__ out)
{
    __shared__ float xs[4 * 528], ys[4 * 528], zs[4 * 528], ss[4 * 528];
    int b = blockIdx.x >> 7;             // 128 blocks per batch
    int q0 = (blockIdx.x & 127) * 64;
    int t = threadIdx.x;
    for (int i = t; i < N4; i += 256) {
        int p = (i >> 9) * 528 + (i & 511);
        const float* s = xyz4 + (size_t)b * N4 * 3 + (size_t)i * 3;
        float x = s[0], y = s[1], z = s[2];
        xs[p] = x; ys[p] = y; zs[p] = z;
        ss[p] = x * x + y * y + z * z;
    }
    __syncthreads();
    int q = q0 + (t >> 2), c = t & 3;
    float qx = xyz_s1[((size_t)b * 3 + 0) * N1 + q];
    float qy = xyz_s1[((size_t)b * 3 + 1) * N1 + q];
    float qz = xyz_s1[((size_t)b * 3 + 2) * N1 + q];
    float nqx = -2.f * qx, nqy = -2.f * qy, nqz = -2.f * qz;
    float sq = qx * qx + qy * qy + qz * qz;
    u64 p0 = ~0ull, p1 = ~0ull, p2 = ~0ull;   // sorted packed (flipped-key<<32 | idx)
    int base = c * 528, nb = c * 512;
    for (int ii = 0; ii < 512; ii += 4) {
        float4 x4 = *(float4*)&xs[base + ii];
        float4 y4 = *(float4*)&ys[base + ii];
        float4 z4 = *(float4*)&zs[base + ii];
        float4 s4 = *(float4*)&ss[base + ii];
#pragma unroll
        for (int j = 0; j < 4; ++j) {
            float dd = fmaf(((const float*)&x4)[j], nqx,
                       fmaf(((const float*)&y4)[j], nqy,
                       fmaf(((const float*)&z4)[j], nqz, ((const float*)&s4)[j])));
            uint u = __float_as_uint(dd);
            u ^= (uint)(((int)u) >> 31) | 0x80000000u;     // order-preserving flip
            u64 e = ((u64)u << 32) | (uint)(nb + ii + j);
            if (e < p2) {
                u64 mm = (e < p1) ? e : p1;
                p2 = (e < p1) ? p1 : e;
                u64 nmm = (mm < p0) ? mm : p0;
                p1 = (mm < p0) ? p0 : mm;
                p0 = nmm;
            }
        }
    }
    // merge the 4 chunk-local top-3 lists (u64 lexicographic == (key, idx) rule)
#pragma unroll
    for (int m = 1; m <= 2; m <<= 1) {
        u64 e0 = __shfl_xor(p0, m, 64);
        u64 e1 = __shfl_xor(p1, m, 64);
        u64 e2 = __shfl_xor(p2, m, 64);
        u64 es[3] = { e0, e1, e2 };
#pragma unroll
        for (int s = 0; s < 3; ++s) {
            u64 e = es[s];
            if (e < p2) {
                u64 mm = (e < p1) ? e : p1;
                p2 = (e < p1) ? p1 : e;
                u64 nmm = (mm < p0) ? mm : p0;
                p1 = (mm < p0) ? p0 : mm;
                p0 = nmm;
            }
        }
    }
    // unpack: reverse order-flip to exact key; idx from low 32
    uint k0 = (uint)(p0 >> 32), k1 = (uint)(p1 >> 32), k2 = (uint)(p2 >> 32);
    int i0 = (int)(p0 & 0xffffffffu), i1 = (int)(p1 & 0xffffffffu), i2 = (int)(p2 & 0xffffffffu);
    float key0 = (k0 & 0x80000000u) ? __uint_as_float(k0 ^ 0x80000000u) : __uint_as_float(~k0);
    float key1 = (k1 & 0x80000000u) ? __uint_as_float(k1 ^ 0x80000000u) : __uint_as_float(~k1);
    float key2 = (k2 & 0x80000000u) ? __uint_as_float(k2 ^ 0x80000000u) : __uint_as_float(~k2);
    float dd0 = fmaxf(key0 + sq, 0.f), dd1 = fmaxf(key1 + sq, 0.f), dd2 = fmaxf(key2 + sq, 0.f);
    float w0 = 1.f / (dd0 + 1e-8f), w1 = 1.f / (dd1 + 1e-8f), w2 = 1.f / (dd2 + 1e-8f);
    float inv = 1.f / (w0 + w1 + w2);
    const float* flr = out + FLOWLR_OFF + (size_t)b * 3 * N4;
    if (c < 3) {
        float v = (w0 * flr[c * N4 + i0] + w1 * flr[c * N4 + i1] + w2 * flr[c * N4 + i2]) * inv;
        out[((size_t)b * 3 + c) * N1 + q] = v;
    }
}

extern "C" void kernel_launch(void* const* d_in, const int* in_sizes, int n_in,
                              void* d_out, int out_size, void* d_ws, size_t ws_size,
                              hipStream_t stream) {
    const float* xyz_s1 = (const float*)d_in[0];
    const float* xyz_s4 = (const float*)d_in[1];
    const float* feats  = (const float*)d_in[2];
    const float* sa1_W1 = (const float*)d_in[3];
    const float* sa1_W2 = (const float*)d_in[5];
    const float* sa2_W1 = (const float*)d_in[7];
    const float* sa2_W2 = (const float*)d_in[9];
    const float* fc_W1  = (const float*)d_in[11];
    const float* fc_b1  = (const float*)d_in[12];
    const float* fc_W2  = (const float*)d_in[13];
    const float* fc_b2  = (const float*)d_in[14];
    float* out = (float*)d_out;

    char* wsb = (char*)d_ws;
    float*  xyz4   = (float*)(wsb + 0);                  // 196608 B
    int*    idx    = (int*)(wsb + 196608);               // 2 MB   -> 2293760
    ushort* featTb = (ushort*)(wsb + 2293760);           // 4 MB   -> 6488064
    ushort* W1b1   = (ushort*)(wsb + 6488064);           // 64 KB  -> 6553600
    ushort* W1b2   = (ushort*)(wsb + 6553600);           // 64 KB  -> 6619136
    ushort* W2b1   = (ushort*)(wsb + 6619136);           // 64 KB  -> 6684672
    ushort* W2b2   = (ushort*)(wsb + 6684672);           // 64 KB  -> 6750208
    float*  statsA = (float*)(wsb + 6750208);            // 8 KB each x4 (contiguous)
    float*  statsB = (float*)(wsb + 6758400);
    float*  statsC = (float*)(wsb + 6766592);
    float*  statsD = (float*)(wsb + 6774784);
    ushort* ymax   = (ushort*)(wsb + 6782976);           // 4 MB  -> 10977280
    ushort* zbuf   = (ushort*)(wsb + 10977280);          // 4 MB  -> 15171584 (bf16 z)

    // ---- setup (prep + feat transpose merged into one dispatch) ----
    k_prep<<<2448, 256, 0, stream>>>(xyz_s4, xyz4, sa1_W1, sa2_W1, sa1_W2, sa2_W2,
                                     W1b1, W1b2, W2b1, W2b2, statsA, feats, featTb);
    k_knn<<<B * (N4 / 8), 512, 0, stream>>>(xyz4, idx);

    // ---- SA1 ----
    k_dense<<<NPTS / 64, 256, 0, stream>>>(featTb, xyz4, W1b1, zbuf, nullptr);
    k_gstats<<<NPTS / 32, 256, 0, stream>>>(zbuf, idx, xyz4, W1b1, statsA);
    k_fused2<<<ROWS_TOTAL / 256, 256, 0, stream>>>(zbuf, idx, xyz4, W1b1, W2b1,
                                                   statsA, statsB, ymax);
    // ---- SA2 (dense folds the SA1 norm+relu of ymax via statsB) ----
    k_dense<<<NPTS / 64, 256, 0, stream>>>(ymax, xyz4, W1b2, zbuf, statsB);
    k_gstats<<<NPTS / 32, 256, 0, stream>>>(zbuf, idx, xyz4, W1b2, statsC);
    k_fused2<<<ROWS_TOTAL / 256, 256, 0, stream>>>(zbuf, idx, xyz4, W1b2, W2b2,
                                                   statsC, statsD, ymax);

    // ---- FC head (folds SA2 norm+relu via statsD) + flow_lr ----
    k_fc<<<(B * N4) / 64, 256, 0, stream>>>(ymax, statsD, fc_W1, fc_b1, fc_W2, fc_b2, out);
    // ---- feature propagation -> flow ----
    k_fp<<<B * (N1 / 64), 256, 0, stream>>>(xyz_s1, xyz4, out);
}

// Round 20
// 314.308 us; speedup vs baseline: 1.0455x; 1.0455x over previous
//
#include <hip/hip_runtime.h>
#include <hip/hip_bf16.h>

#define B 8
#define N1 8192
#define N4 2048
#define CH 128
#define KNN 32
#define ROWS_PER_B (N4 * KNN)          // 65536 rows per batch in the [B,N,K] flattening
#define ROWS_TOTAL (B * ROWS_PER_B)    // 524288
#define NPTS (B * N4)                  // 16384 total points
#define FLOWLR_OFF (B * 3 * N1)        // flow_lr starts after flow in d_out

typedef unsigned int uint;
typedef unsigned short ushort;
typedef __attribute__((ext_vector_type(8))) short short8;
typedef __attribute__((ext_vector_type(4))) float f32x4;

union U16 { uint4 u; short8 s; };

__device__ __forceinline__ float bf2f(ushort u) {
    union { uint i; float f; } v; v.i = ((uint)u) << 16; return v.f;
}
__device__ __forceinline__ ushort f2b(float f) {
    __hip_bfloat16 h = __float2bfloat16(f);
    return *(ushort*)&h;
}

// ---------------- prep (merged): W converters + xyz transpose + stats zero + feats transpose ----------------
// blocks [0,400): elementwise prep; blocks [400,2448): feat-transpose tiles (flat 256 threads as 32x8).
__global__ void k_prep(const float* __restrict__ xyz_s4, float* __restrict__ xyz4,
                       const float* __restrict__ sa1_W1, const float* __restrict__ sa2_W1,
                       const float* __restrict__ sa1_W2, const float* __restrict__ sa2_W2,
                       ushort* __restrict__ W1b1, ushort* __restrict__ W1b2,
                       ushort* __restrict__ W2b1, ushort* __restrict__ W2b2,
                       float* __restrict__ stats,
                       const float* __restrict__ feats, ushort* __restrict__ featTb)
{
    __shared__ float tile[32][33];
    if (blockIdx.x < 400) {
        int i = blockIdx.x * 256 + threadIdx.x;
        if (i < 43008) {
            const float* W = (i < 21504) ? sa1_W1 : sa2_W1;
            ushort* o = (i < 21504) ? W1b1 : W1b2;
            int j = (i < 21504) ? i : i - 21504;
            int d = j / 168, c = j - d * 168;
            float v = 0.f;
            if (c < 128)      v = W[d * 131 + 3 + c];
            else if (c < 131) v = W[d * 131 + (c - 128)];
            o[j] = f2b(v);
        } else if (i < 77824) {
            const float* W = (i < 60416) ? sa1_W2 : sa2_W2;
            ushort* o = (i < 60416) ? W2b1 : W2b2;
            int j = (i < 60416) ? i - 43008 : i - 60416;
            int d = j / 136, c = j - d * 136;
            o[j] = (c < 128) ? f2b(W[d * 128 + c]) : (ushort)0;
        } else if (i < 94208) {
            int g = i - 77824;
            int b = g >> 11, n = g & (N4 - 1);
            xyz4[g * 3 + 0] = xyz_s4[(b * 3 + 0) * N4 + n];
            xyz4[g * 3 + 1] = xyz_s4[(b * 3 + 1) * N4 + n];
            xyz4[g * 3 + 2] = xyz_s4[(b * 3 + 2) * N4 + n];
        } else if (i < 102400) {
            stats[i - 94208] = 0.f;    // zeros statsA..statsD (contiguous 8192 floats)
        }
    } else {
        int f = blockIdx.x - 400;       // 2048 tiles: b(8) x nb(64) x cb(4)
        int b = f >> 8, rem = f & 255, nb = rem >> 2, cb = rem & 3;
        int tx = threadIdx.x & 31, ty = threadIdx.x >> 5;   // 32 x 8
        int n0 = nb * 32, c0 = cb * 32;
#pragma unroll
        for (int i = 0; i < 4; ++i) {
            int c = c0 + ty + 8 * i;
            tile[ty + 8 * i][tx] = feats[((size_t)b * CH + c) * N4 + n0 + tx];
        }
        __syncthreads();
#pragma unroll
        for (int i = 0; i < 4; ++i) {
            int n = n0 + ty + 8 * i;
            featTb[((size_t)b * N4 + n) * CH + c0 + tx] = f2b(tile[tx][ty + 8 * i]);
        }
    }
}

// ---------------- KNN via exact threshold-select (interpolation search + order-statistic gap exit) ----------------
__global__ __launch_bounds__(512) void k_knn(const float* __restrict__ xyz4, int* __restrict__ idxout) {
    __shared__ float pts[N4 * 3];
    int b = blockIdx.x >> 8;            // 256 blocks per batch
    int qbase = (blockIdx.x & 255) * 8;
    for (int i = threadIdx.x; i < N4 * 3; i += 512) pts[i] = xyz4[(size_t)b * N4 * 3 + i];
    __syncthreads();
    int wave = threadIdx.x >> 6, lane = threadIdx.x & 63;
    int qn = qbase + wave;
    float qx = pts[qn * 3 + 0], qy = pts[qn * 3 + 1], qz = pts[qn * 3 + 2];
    float d[32];
#pragma unroll
    for (int t = 0; t < 32; ++t) {
        int c = t * 64 + lane;
        float dx = pts[c * 3 + 0] - qx;
        float dy = pts[c * 3 + 1] - qy;
        float dz = pts[c * 3 + 2] - qz;
        d[t] = dx * dx + dy * dy + dz * dz;
    }
    uint lo = 0u, hi = 0x7F800000u;
    int cLT = 0, cHI = N4;
    float T;
    bool strict = false;
    int it = 0;
    for (;;) {
        if (hi - lo <= 1u) { T = __uint_as_float(lo); break; }
        if (cHI - cLT == 1) {
            float flo = __uint_as_float(lo), fhi = __uint_as_float(hi);
            float m = 3.4e38f;
#pragma unroll
            for (int t = 0; t < 32; ++t) {
                float dv = d[t];
                if (dv >= flo && dv < fhi) m = fminf(m, dv);
            }
#pragma unroll
            for (int s = 1; s < 64; s <<= 1) m = fminf(m, __shfl_xor(m, s, 64));
            T = m;
            break;
        }
        uint mid;
        if ((it & 3) == 0) {
            mid = (lo + hi) >> 1;
        } else {
            float flo = __uint_as_float(lo), fhi = __uint_as_float(hi);
            float fm = flo + (fhi - flo) * ((float)(KNN - cLT) / (float)(cHI - cLT));
            mid = __float_as_uint(fm);
            if (mid <= lo) mid = lo + 1u;
            if (mid >= hi) mid = hi - 1u;
        }
        float fmid = __uint_as_float(mid);
        int c = 0;
#pragma unroll
        for (int t = 0; t < 32; ++t) c += __popcll(__ballot(d[t] < fmid));
        if (c == KNN) { T = fmid; strict = true; break; }
        if (c < KNN) { lo = mid; cLT = c; } else { hi = mid; cHI = c; }
        ++it;
    }
    int outb = (b * N4 + qn) * KNN;
    unsigned long long lmlt = (1ull << lane) - 1ull;
    if (strict) {
        int baseLT = 0;
#pragma unroll
        for (int t = 0; t < 32; ++t) {
            bool lt = d[t] < T;
            unsigned long long m = __ballot(lt);
            if (lt) idxout[outb + baseLT + __popcll(m & lmlt)] = t * 64 + lane;
            baseLT += __popcll(m);
        }
    } else {
        int baseLT = 0, baseEQ = cLT;
#pragma unroll
        for (int t = 0; t < 32; ++t) {
            bool lt = d[t] < T;
            unsigned long long m = __ballot(lt);
            if (lt) idxout[outb + baseLT + __popcll(m & lmlt)] = t * 64 + lane;
            baseLT += __popcll(m);
            bool eq = (d[t] == T);
            unsigned long long me = __ballot(eq);
            if (eq) {
                int rk = baseEQ + __popcll(me & lmlt);
                if (rk < KNN) idxout[outb + rk] = t * 64 + lane;
            }
            baseEQ += __popcll(me);
        }
    }
}

// ---------------- dense z GEMM: z[p] = [in_p | xyz_p] @ W1^T -> bf16 out (LDS repack, coalesced) ----------------
__global__ __launch_bounds__(256) void k_dense(
    const ushort* __restrict__ Fb, const float* __restrict__ xyz4,
    const ushort* __restrict__ W1b, ushort* __restrict__ z,
    const float* __restrict__ stats)
{
    __shared__ __align__(16) ushort hs[64][168];
    __shared__ float sinvs[128], sprem[128];   // sinv, mean*sinv
    int t = threadIdx.x;
    int r = t >> 2, q = t & 3;
    int l = t & 63, w = t >> 6, lr = l & 15, lg = l >> 4;
    int g0 = blockIdx.x * 64;
    int b = g0 >> 11;                    // 2048 points per batch
    if (stats) {
        if (t < 128) {
            float s = stats[b * CH + t], q2 = stats[B * CH + b * CH + t];
            float mean = s * (1.f / ROWS_PER_B);
            float var = q2 * (1.f / ROWS_PER_B) - mean * mean;
            float iv = rsqrtf(var + 1e-5f);
            sinvs[t] = iv; sprem[t] = mean * iv;
        }
        __syncthreads();
    }
    {
        int p = g0 + r;
        const uint4* src = (const uint4*)(Fb + (size_t)p * CH) + q * 4;
        uint4* dst = (uint4*)&hs[r][q * 32];
        if (stats) {
#pragma unroll
            for (int m = 0; m < 4; ++m) {
                uint4 v = src[m];
                const uint* pv = (const uint*)&v;
                ushort o[8];
#pragma unroll
                for (int e = 0; e < 4; ++e) {
                    int c = q * 32 + m * 8 + e * 2;
                    o[e * 2]     = f2b(fmaxf(fmaf(bf2f((ushort)(pv[e] & 0xffff)), sinvs[c],     -sprem[c]),     0.f));
                    o[e * 2 + 1] = f2b(fmaxf(fmaf(bf2f((ushort)(pv[e] >> 16)),    sinvs[c + 1], -sprem[c + 1]), 0.f));
                }
                dst[m] = *(uint4*)o;
            }
        } else {
#pragma unroll
            for (int m = 0; m < 4; ++m) dst[m] = src[m];
        }
        uint4 zz = make_uint4(0, 0, 0, 0);
        *(uint4*)&hs[r][128 + q * 8] = zz;
        if (q == 0) {
            *(uint4*)&hs[r][160] = zz;
            hs[r][128] = f2b(xyz4[p * 3 + 0]);
            hs[r][129] = f2b(xyz4[p * 3 + 1]);
            hs[r][130] = f2b(xyz4[p * 3 + 2]);
        }
    }
    U16 bf[5][2];
#pragma unroll
    for (int kc = 0; kc < 5; ++kc)
#pragma unroll
        for (int jj = 0; jj < 2; ++jj)
            bf[kc][jj].u = *(const uint4*)&W1b[(size_t)(w * 32 + jj * 16 + lr) * 168 + kc * 32 + lg * 8];
    __syncthreads();
    f32x4 acc[4][2];
    f32x4 z4 = {0.f, 0.f, 0.f, 0.f};
#pragma unroll
    for (int i = 0; i < 4; ++i) { acc[i][0] = z4; acc[i][1] = z4; }
#pragma unroll
    for (int kc = 0; kc < 5; ++kc) {
        U16 a[4];
#pragma unroll
        for (int i = 0; i < 4; ++i) a[i].u = *(const uint4*)&hs[16 * i + lr][kc * 32 + lg * 8];
#pragma unroll
        for (int i = 0; i < 4; ++i)
#pragma unroll
            for (int jj = 0; jj < 2; ++jj)
                acc[i][jj] = __builtin_amdgcn_mfma_f32_16x16x32_bf16(a[i].s, bf[kc][jj].s, acc[i][jj], 0, 0, 0);
    }
    __syncthreads();   // hs reads done -> reuse as bf16 repack buffer
#pragma unroll
    for (int jj = 0; jj < 2; ++jj)
#pragma unroll
        for (int i = 0; i < 4; ++i)
#pragma unroll
            for (int rg = 0; rg < 4; ++rg)
                hs[16 * i + lg * 4 + rg][w * 32 + jj * 16 + lr] = f2b(acc[i][jj][rg]);
    __syncthreads();
    {
        uint4* dst = (uint4*)(z + (size_t)(g0 + r) * CH + q * 32);
#pragma unroll
        for (int m = 0; m < 4; ++m) dst[m] = *(const uint4*)&hs[r][q * 32 + m * 8];
    }
}

// ---------------- gather-stats: per-(b,c) sum/sumsq of y1 = z[j]-u[n]; z bf16, u on the fly ----------------
__global__ __launch_bounds__(256) void k_gstats(
    const ushort* __restrict__ z, const int* __restrict__ idx,
    const float* __restrict__ xyz4, const ushort* __restrict__ W1b,
    float* __restrict__ stats)
{
    __shared__ int idxs[32 * KNN];
    __shared__ float sacc[128], sqacc[128];
    __shared__ ushort w1x[384];          // [c][a], c*3+a
    int t = threadIdx.x;
    int gpb = blockIdx.x * 32;
    int b = gpb >> 11;
    for (int ii = t; ii < 32 * KNN; ii += 256) idxs[ii] = idx[(size_t)gpb * KNN + ii];
    if (t < 128) {
        sacc[t] = 0.f; sqacc[t] = 0.f;
        w1x[t * 3 + 0] = W1b[t * 168 + 128];
        w1x[t * 3 + 1] = W1b[t * 168 + 129];
        w1x[t * 3 + 2] = W1b[t * 168 + 130];
    }
    __syncthreads();
    int li = t >> 3, cq = (t & 7) * 16;
    int gp = gpb + li;
    float s[16], qa[16];
#pragma unroll
    for (int m = 0; m < 16; ++m) { s[m] = 0.f; qa[m] = 0.f; }
    int zb = b * N4;
#pragma unroll 4
    for (int k = 0; k < KNN; ++k) {
        int j = idxs[li * KNN + k];
        const uint4* zr = (const uint4*)(z + (size_t)(zb + j) * CH + cq);  // 16 bf16 = 2x uint4
        uint4 v0 = zr[0], v1 = zr[1];
        const uint* pv = (const uint*)&v0;
#pragma unroll
        for (int u8 = 0; u8 < 8; ++u8) {
            uint vv = (u8 < 4) ? pv[u8] : ((const uint*)&v1)[u8 - 4];
            float f0 = bf2f((ushort)(vv & 0xffff));
            float f1 = bf2f((ushort)(vv >> 16));
            s[u8 * 2] += f0;     qa[u8 * 2] += f0 * f0;
            s[u8 * 2 + 1] += f1; qa[u8 * 2 + 1] += f1 * f1;
        }
    }
    float x = bf2f(f2b(xyz4[gp * 3 + 0]));
    float y = bf2f(f2b(xyz4[gp * 3 + 1]));
    float zc = bf2f(f2b(xyz4[gp * 3 + 2]));
#pragma unroll
    for (int m = 0; m < 16; ++m) {
        int c = cq + m;
        float uu = x * bf2f(w1x[c * 3]) + y * bf2f(w1x[c * 3 + 1]) + zc * bf2f(w1x[c * 3 + 2]);
        float ss = s[m], qq = qa[m];
        atomicAdd(&sacc[c], ss - 32.f * uu);
        atomicAdd(&sqacc[c], qq - 2.f * uu * ss + 32.f * uu * uu);
    }
    __syncthreads();
    if (t < 128) {
        atomicAdd(&stats[b * CH + t], sacc[t]);
        atomicAdd(&stats[B * CH + b * CH + t], sqacc[t]);
    }
}

// ---------------- fused pass: 256 rows/block, dbuf LDS; z bf16; affine-folded normalization ----------------
__global__ __launch_bounds__(256) void k_fused2(
    const ushort* __restrict__ z, const int* __restrict__ idx,
    const float* __restrict__ xyz4, const ushort* __restrict__ W1b,
    const ushort* __restrict__ W2b, const float* __restrict__ stats1,
    float* __restrict__ stats2, ushort* __restrict__ ymax)
{
    __shared__ __align__(16) ushort hs[2][64][136];
    __shared__ float sinvs[128], smean[128];
    __shared__ float pre[8][128];        // (u + mean) * sinv per point
    __shared__ ushort w1x[384];
    int t = threadIdx.x;
    int g0 = blockIdx.x * 256;          // 256 rows = 8 points
    int b = g0 >> 16;
    int gp0 = g0 >> 5;
    int l = t & 63, w = t >> 6, lr = l & 15, lg = l >> 4;
    U16 b2f[4][2];
#pragma unroll
    for (int kc = 0; kc < 4; ++kc)
#pragma unroll
        for (int jj = 0; jj < 2; ++jj)
            b2f[kc][jj].u = *(const uint4*)&W2b[(size_t)(w * 32 + jj * 16 + lr) * 136 + kc * 32 + lg * 8];
    if (t < 128) {
        float s = stats1[b * CH + t], q2 = stats1[B * CH + b * CH + t];
        float mean = s * (1.f / ROWS_PER_B);
        float var = q2 * (1.f / ROWS_PER_B) - mean * mean;
        float iv = rsqrtf(var + 1e-5f);
        sinvs[t] = iv; smean[t] = mean;
        w1x[t * 3 + 0] = W1b[t * 168 + 128];
        w1x[t * 3 + 1] = W1b[t * 168 + 129];
        w1x[t * 3 + 2] = W1b[t * 168 + 130];
    }
    __syncthreads();
    {   // pre[p][c] = (u[p][c] + mean[c]) * sinv[c]; 8 points x 128 cols, 4 cols/thread
        int p = t >> 5, i = t & 31;
        float x = bf2f(f2b(xyz4[(gp0 + p) * 3 + 0]));
        float y = bf2f(f2b(xyz4[(gp0 + p) * 3 + 1]));
        float zc = bf2f(f2b(xyz4[(gp0 + p) * 3 + 2]));
#pragma unroll
        for (int jj = 0; jj < 4; ++jj) {
            int c = i * 4 + jj;
            float uu = x * bf2f(w1x[c * 3]) + y * bf2f(w1x[c * 3 + 1]) + zc * bf2f(w1x[c * 3 + 2]);
            pre[p][c] = (uu + smean[c]) * sinvs[c];
        }
    }
    int r = t >> 2, q = t & 3;
    uint4 zv[4];
    {
        int j = idx[g0 + r];
        const uint4* zr = (const uint4*)(z + (size_t)(b * N4 + j) * CH + q * 32);
#pragma unroll
        for (int m = 0; m < 4; ++m) zv[m] = zr[m];
    }
    float sA[2] = {0.f, 0.f}, qA[2] = {0.f, 0.f};
    f32x4 z4 = {0.f, 0.f, 0.f, 0.f};
    __syncthreads();   // sinvs/pre ready
    for (int st = 0; st < 4; ++st) {
        ushort (*buf)[136] = hs[st & 1];
        {
            int urow = (st * 64 + r) >> 5;
#pragma unroll
            for (int mm = 0; mm < 4; ++mm) {
                const uint* pv = (const uint*)&zv[mm];
                ushort o[8];
#pragma unroll
                for (int e = 0; e < 4; ++e) {
                    int c = q * 32 + mm * 8 + e * 2;
                    float f0 = bf2f((ushort)(pv[e] & 0xffff));
                    float f1 = bf2f((ushort)(pv[e] >> 16));
                    o[e * 2]     = f2b(fmaxf(fmaf(f0, sinvs[c],     -pre[urow][c]),     0.f));
                    o[e * 2 + 1] = f2b(fmaxf(fmaf(f1, sinvs[c + 1], -pre[urow][c + 1]), 0.f));
                }
                *(uint4*)&buf[r][q * 32 + mm * 8] = *(uint4*)o;
            }
            if (q == 0) { uint4 zz = make_uint4(0, 0, 0, 0); *(uint4*)&buf[r][128] = zz; }
        }
        __syncthreads();
        if (st < 3) {
            int j = idx[g0 + (st + 1) * 64 + r];
            const uint4* zr = (const uint4*)(z + (size_t)(b * N4 + j) * CH + q * 32);
#pragma unroll
            for (int m = 0; m < 4; ++m) zv[m] = zr[m];
        }
        f32x4 acc[4][2];
#pragma unroll
        for (int i = 0; i < 4; ++i) { acc[i][0] = z4; acc[i][1] = z4; }
#pragma unroll
        for (int kc = 0; kc < 4; ++kc) {
            U16 a[4];
#pragma unroll
            for (int i = 0; i < 4; ++i) a[i].u = *(const uint4*)&buf[16 * i + lr][kc * 32 + lg * 8];
#pragma unroll
            for (int i = 0; i < 4; ++i)
#pragma unroll
                for (int jj = 0; jj < 2; ++jj)
                    acc[i][jj] = __builtin_amdgcn_mfma_f32_16x16x32_bf16(a[i].s, b2f[kc][jj].s, acc[i][jj], 0, 0, 0);
        }
        int gpA = gp0 + st * 2;
#pragma unroll
        for (int jj = 0; jj < 2; ++jj) {
            int c = w * 32 + jj * 16 + lr;
            float m0 = -3.4e38f, m1 = -3.4e38f;
#pragma unroll
            for (int i = 0; i < 4; ++i)
#pragma unroll
                for (int rg = 0; rg < 4; ++rg) {
                    float v = acc[i][jj][rg];
                    sA[jj] += v; qA[jj] += v * v;
                    if (i < 2) m0 = fmaxf(m0, v); else m1 = fmaxf(m1, v);
                }
            m0 = fmaxf(m0, __shfl_xor(m0, 16, 64)); m0 = fmaxf(m0, __shfl_xor(m0, 32, 64));
            m1 = fmaxf(m1, __shfl_xor(m1, 16, 64)); m1 = fmaxf(m1, __shfl_xor(m1, 32, 64));
            if (lg == 0) {
                ymax[(size_t)gpA * CH + c] = f2b(m0);
                ymax[(size_t)(gpA + 1) * CH + c] = f2b(m1);
            }
        }
    }
#pragma unroll
    for (int jj = 0; jj < 2; ++jj) {
        int c = w * 32 + jj * 16 + lr;
        float ss = sA[jj], qq = qA[jj];
        ss += __shfl_xor(ss, 16, 64); ss += __shfl_xor(ss, 32, 64);
        qq += __shfl_xor(qq, 16, 64); qq += __shfl_xor(qq, 32, 64);
        if (lg == 0) {
            atomicAdd(&stats2[b * CH + c], ss);
            atomicAdd(&stats2[B * CH + b * CH + c], qq);
        }
    }
}

// ---------------- FC head: relu(normrelu(ymax)@W1^T+b1) @ W2^T + b2 -> flow_lr [B,3,N4] ----------------
__global__ __launch_bounds__(256, 1) void k_fc(
    const ushort* __restrict__ Ymax, const float* __restrict__ stats,
    const float* __restrict__ W1, const float* __restrict__ b1,
    const float* __restrict__ W2, const float* __restrict__ b2,
    float* __restrict__ out)
{
    __shared__ float hs[64][132];
    __shared__ float ws[128][132];
    __shared__ float sinvs[128], sprem[128];
    int t = threadIdx.x;
    int g0 = blockIdx.x * 64;
    int b = g0 >> 11;
    if (t < 128) {
        float s = stats[b * CH + t], q2 = stats[B * CH + b * CH + t];
        float mean = s * (1.f / ROWS_PER_B);
        float var = q2 * (1.f / ROWS_PER_B) - mean * mean;
        float iv = rsqrtf(var + 1e-5f);
        sinvs[t] = iv; sprem[t] = mean * iv;
    }
    for (int i = t; i < 128 * 132; i += 256) {
        int dd = i / 132, c = i - dd * 132;
        ws[dd][c] = (c < 128) ? W1[dd * 128 + c] : 0.f;
    }
    __syncthreads();
    int r = t >> 2, q = t & 3;
    {
        const uint4* Xrow = (const uint4*)(Ymax + (size_t)(g0 + r) * CH + q * 32);
#pragma unroll
        for (int m = 0; m < 4; ++m) {
            uint4 v = Xrow[m];
            const uint* pv = (const uint*)&v;
            int c0 = q * 32 + m * 8;
#pragma unroll
            for (int e = 0; e < 4; ++e) {
                int c = c0 + 2 * e;
                hs[r][c]     = fmaxf(fmaf(bf2f((ushort)(pv[e] & 0xffff)), sinvs[c],     -sprem[c]),     0.f);
                hs[r][c + 1] = fmaxf(fmaf(bf2f((ushort)(pv[e] >> 16)),    sinvs[c + 1], -sprem[c + 1]), 0.f);
            }
        }
        if (q == 0) *(float4*)&hs[r][128] = make_float4(0.f, 0.f, 0.f, 0.f);
    }
    __syncthreads();
    int tx = t & 15, ty = t >> 4;
    float acc[4][8];
#pragma unroll
    for (int i = 0; i < 4; ++i)
#pragma unroll
        for (int jj = 0; jj < 8; ++jj) acc[i][jj] = 0.f;
    for (int kb = 0; kb < 33; ++kb) {
        float4 a[4]; float4 w[8];
#pragma unroll
        for (int i = 0; i < 4; ++i) a[i] = *(float4*)&hs[ty * 4 + i][kb * 4];
#pragma unroll
        for (int jj = 0; jj < 8; ++jj) w[jj] = *(float4*)&ws[tx + 16 * jj][kb * 4];
#pragma unroll
        for (int i = 0; i < 4; ++i)
#pragma unroll
            for (int jj = 0; jj < 8; ++jj)
                acc[i][jj] += a[i].x * w[jj].x + a[i].y * w[jj].y
                            + a[i].z * w[jj].z + a[i].w * w[jj].w;
    }
    __syncthreads();
#pragma unroll
    for (int jj = 0; jj < 8; ++jj) {
        int c = tx + 16 * jj;
        float bias = b1[c];
#pragma unroll
        for (int i = 0; i < 4; ++i)
            hs[ty * 4 + i][c] = fmaxf(acc[i][jj] + bias, 0.f);
    }
    __syncthreads();
    if (t < 192) {
        int rr = t / 3, o = t - rr * 3;
        float sum = b2[o];
        for (int c = 0; c < 128; ++c) sum += hs[rr][c] * W2[o * 128 + c];
        int g = g0 + rr;
        int bb = g >> 11, n = g & (N4 - 1);
        out[FLOWLR_OFF + ((size_t)bb * 3 + o) * N4 + n] = sum;
    }
}

// ---------------- feature propagation: 3-NN inverse-sqdist interp onto xyz1 ----------------
__global__ __launch_bounds__(256) void k_fp(
    const float* __restrict__ xyz_s1, const float* __restrict__ xyz4,
    float* __restrict__ out)
{
    __shared__ float xs[4 * 528], ys[4 * 528], zs[4 * 528], ss[4 * 528];
    int b = blockIdx.x >> 7;             // 128 blocks per batch
    int q0 = (blockIdx.x & 127) * 64;
    int t = threadIdx.x;
    for (int i = t; i < N4; i += 256) {
        int p = (i >> 9) * 528 + (i & 511);
        const float* s = xyz4 + (size_t)b * N4 * 3 + (size_t)i * 3;
        float x = s[0], y = s[1], z = s[2];
        xs[p] = x; ys[p] = y; zs[p] = z;
        ss[p] = x * x + y * y + z * z;
    }
    __syncthreads();
    int q = q0 + (t >> 2), c = t & 3;
    float qx = xyz_s1[((size_t)b * 3 + 0) * N1 + q];
    float qy = xyz_s1[((size_t)b * 3 + 1) * N1 + q];
    float qz = xyz_s1[((size_t)b * 3 + 2) * N1 + q];
    float nqx = -2.f * qx, nqy = -2.f * qy, nqz = -2.f * qz;
    float sq = qx * qx + qy * qy + qz * qz;
    float d0 = 3.4e38f, d1 = 3.4e38f, d2 = 3.4e38f;   // KEYS (= d^2 - |q|^2)
    int i0 = 0, i1 = 0, i2 = 0;
    int base = c * 528, nb = c * 512;
    for (int ii = 0; ii < 512; ii += 4) {
        float4 x4 = *(float4*)&xs[base + ii];
        float4 y4 = *(float4*)&ys[base + ii];
        float4 z4 = *(float4*)&zs[base + ii];
        float4 s4 = *(float4*)&ss[base + ii];
#pragma unroll
        for (int j = 0; j < 4; ++j) {
            float dd = fmaf(((const float*)&x4)[j], nqx,
                       fmaf(((const float*)&y4)[j], nqy,
                       fmaf(((const float*)&z4)[j], nqz, ((const float*)&s4)[j])));
            if (dd < d2) {
                int n = nb + ii + j;
                if (dd < d0)      { d2 = d1; i2 = i1; d1 = d0; i1 = i0; d0 = dd; i0 = n; }
                else if (dd < d1) { d2 = d1; i2 = i1; d1 = dd; i1 = n; }
                else              { d2 = dd; i2 = n; }
            }
        }
    }
#pragma unroll
    for (int m = 1; m <= 2; m <<= 1) {
        float e0 = __shfl_xor(d0, m, 64), e1 = __shfl_xor(d1, m, 64), e2 = __shfl_xor(d2, m, 64);
        int   j0 = __shfl_xor(i0, m, 64), j1 = __shfl_xor(i1, m, 64), j2 = __shfl_xor(i2, m, 64);
        float ed[3] = { e0, e1, e2 }; int ej[3] = { j0, j1, j2 };
#pragma unroll
        for (int s = 0; s < 3; ++s) {
            float dd = ed[s]; int jn = ej[s];
            bool lt2 = dd < d2 || (dd == d2 && jn < i2);
            if (lt2) {
                bool lt0 = dd < d0 || (dd == d0 && jn < i0);
                bool lt1 = dd < d1 || (dd == d1 && jn < i1);
                if (lt0)      { d2 = d1; i2 = i1; d1 = d0; i1 = i0; d0 = dd; i0 = jn; }
                else if (lt1) { d2 = d1; i2 = i1; d1 = dd; i1 = jn; }
                else          { d2 = dd; i2 = jn; }
            }
        }
    }
    float dd0 = fmaxf(d0 + sq, 0.f), dd1 = fmaxf(d1 + sq, 0.f), dd2 = fmaxf(d2 + sq, 0.f);
    float w0 = 1.f / (dd0 + 1e-8f), w1 = 1.f / (dd1 + 1e-8f), w2 = 1.f / (dd2 + 1e-8f);
    float inv = 1.f / (w0 + w1 + w2);
    const float* flr = out + FLOWLR_OFF + (size_t)b * 3 * N4;
    if (c < 3) {
        float v = (w0 * flr[c * N4 + i0] + w1 * flr[c * N4 + i1] + w2 * flr[c * N4 + i2]) * inv;
        out[((size_t)b * 3 + c) * N1 + q] = v;
    }
}

extern "C" void kernel_launch(void* const* d_in, const int* in_sizes, int n_in,
                              void* d_out, int out_size, void* d_ws, size_t ws_size,
                              hipStream_t stream) {
    const float* xyz_s1 = (const float*)d_in[0];
    const float* xyz_s4 = (const float*)d_in[1];
    const float* feats  = (const float*)d_in[2];
    const float* sa1_W1 = (const float*)d_in[3];
    const float* sa1_W2 = (const float*)d_in[5];
    const float* sa2_W1 = (const float*)d_in[7];
    const float* sa2_W2 = (const float*)d_in[9];
    const float* fc_W1  = (const float*)d_in[11];
    const float* fc_b1  = (const float*)d_in[12];
    const float* fc_W2  = (const float*)d_in[13];
    const float* fc_b2  = (const float*)d_in[14];
    float* out = (float*)d_out;

    char* wsb = (char*)d_ws;
    float*  xyz4   = (float*)(wsb + 0);                  // 196608 B
    int*    idx    = (int*)(wsb + 196608);               // 2 MB   -> 2293760
    ushort* featTb = (ushort*)(wsb + 2293760);           // 4 MB   -> 6488064
    ushort* W1b1   = (ushort*)(wsb + 6488064);           // 64 KB  -> 6553600
    ushort* W1b2   = (ushort*)(wsb + 6553600);           // 64 KB  -> 6619136
    ushort* W2b1   = (ushort*)(wsb + 6619136);           // 64 KB  -> 6684672
    ushort* W2b2   = (ushort*)(wsb + 6684672);           // 64 KB  -> 6750208
    float*  statsA = (float*)(wsb + 6750208);            // 8 KB each x4 (contiguous)
    float*  statsB = (float*)(wsb + 6758400);
    float*  statsC = (float*)(wsb + 6766592);
    float*  statsD = (float*)(wsb + 6774784);
    ushort* ymax   = (ushort*)(wsb + 6782976);           // 4 MB  -> 10977280
    ushort* zbuf   = (ushort*)(wsb + 10977280);          // 4 MB  -> 15171584 (bf16 z)

    // ---- setup (prep + feat transpose merged into one dispatch) ----
    k_prep<<<2448, 256, 0, stream>>>(xyz_s4, xyz4, sa1_W1, sa2_W1, sa1_W2, sa2_W2,
                                     W1b1, W1b2, W2b1, W2b2, statsA, feats, featTb);
    k_knn<<<B * (N4 / 8), 512, 0, stream>>>(xyz4, idx);

    // ---- SA1 ----
    k_dense<<<NPTS / 64, 256, 0, stream>>>(featTb, xyz4, W1b1, zbuf, nullptr);
    k_gstats<<<NPTS / 32, 256, 0, stream>>>(zbuf, idx, xyz4, W1b1, statsA);
    k_fused2<<<ROWS_TOTAL / 256, 256, 0, stream>>>(zbuf, idx, xyz4, W1b1, W2b1,
                                                   statsA, statsB, ymax);
    // ---- SA2 (dense folds the SA1 norm+relu of ymax via statsB) ----
    k_dense<<<NPTS / 64, 256, 0, stream>>>(ymax, xyz4, W1b2, zbuf, statsB);
    k_gstats<<<NPTS / 32, 256, 0, stream>>>(zbuf, idx, xyz4, W1b2, statsC);
    k_fused2<<<ROWS_TOTAL / 256, 256, 0, stream>>>(zbuf, idx, xyz4, W1b2, W2b2,
                                                   statsC, statsD, ymax);

    // ---- FC head (folds SA2 norm+relu via statsD) + flow_lr ----
    k_fc<<<(B * N4) / 64, 256, 0, stream>>>(ymax, statsD, fc_W1, fc_b1, fc_W2, fc_b2, out);
    // ---- feature propagation -> flow ----
    k_fp<<<B * (N1 / 64), 256, 0, stream>>>(xyz_s1, xyz4, out);
}